// Round 1
// baseline (418.302 us; speedup 1.0000x reference)
//
#include <hip/hip_runtime.h>
#include <cstdint>
#include <cstddef>

typedef __bf16 bf16;
typedef float f32x4 __attribute__((ext_vector_type(4)));
typedef __bf16 bf16x8 __attribute__((ext_vector_type(8)));

#define MFMA16(a, b, c) __builtin_amdgcn_mfma_f32_16x16x32_bf16((a), (b), (c), 0, 0, 0)

__device__ __forceinline__ void gload_lds16(const void* g, void* l) {
  __builtin_amdgcn_global_load_lds((__attribute__((address_space(1))) void*)g,
                                   (__attribute__((address_space(3))) void*)l,
                                   16, 0, 0);
}

// ---------------------------------------------------------------------------
// Weight transpose + f32->bf16 convert: W[K][N] -> Wt[N][K]
// ---------------------------------------------------------------------------
__global__ __launch_bounds__(256) void wconv_kernel(const float* __restrict__ W,
                                                    bf16* __restrict__ Wt, int K, int N) {
  __shared__ float tile[32][33];
  const int n0 = blockIdx.x * 32, k0 = blockIdx.y * 32;
  const int t = threadIdx.x;
  const int c = t & 31, r = t >> 5;  // r in 0..7
#pragma unroll
  for (int i = 0; i < 4; ++i)
    tile[r + i * 8][c] = W[(size_t)(k0 + r + i * 8) * N + n0 + c];
  __syncthreads();
#pragma unroll
  for (int i = 0; i < 4; ++i)
    Wt[(size_t)(n0 + r + i * 8) * K + k0 + c] = (bf16)tile[c][r + i * 8];
}

// ---------------------------------------------------------------------------
// LayerNorm (center=False per keras semantics: subtract mean, no beta) -> bf16
// D = 768, one block per row, 256 threads x 3 elements
// ---------------------------------------------------------------------------
__global__ __launch_bounds__(256) void ln_kernel(const float* __restrict__ X,
                                                 const float* __restrict__ gamma,
                                                 bf16* __restrict__ out) {
  const int row = blockIdx.x, t = threadIdx.x;
  const float* xr = X + (size_t)row * 768;
  float v0 = xr[t], v1 = xr[t + 256], v2 = xr[t + 512];
  float s = v0 + v1 + v2;
  float s2 = v0 * v0 + v1 * v1 + v2 * v2;
#pragma unroll
  for (int m = 1; m <= 32; m <<= 1) {
    s += __shfl_xor(s, m, 64);
    s2 += __shfl_xor(s2, m, 64);
  }
  __shared__ float red[8];
  const int w = t >> 6, lane = t & 63;
  if (lane == 0) { red[w] = s; red[4 + w] = s2; }
  __syncthreads();
  s = red[0] + red[1] + red[2] + red[3];
  s2 = red[4] + red[5] + red[6] + red[7];
  const float mu = s * (1.f / 768.f);
  const float var = s2 * (1.f / 768.f) - mu * mu;
  const float rs = rsqrtf(var + 1e-5f);
  out[(size_t)row * 768 + t] = (bf16)((v0 - mu) * rs * gamma[t]);
  out[(size_t)row * 768 + t + 256] = (bf16)((v1 - mu) * rs * gamma[t + 256]);
  out[(size_t)row * 768 + t + 512] = (bf16)((v2 - mu) * rs * gamma[t + 512]);
}

// ---------------------------------------------------------------------------
// NT GEMM: C[M][N] = A[M][K](bf16) * Bt[N][K](bf16)^T  (+ optional f32 residual)
// 128x128 tile, BK=64, 4 waves (2x2 of 64x64), global_load_lds + XOR swizzle
// ---------------------------------------------------------------------------
template <bool RES>
__global__ __launch_bounds__(256) void gemm_bt(const bf16* __restrict__ A,
                                               const bf16* __restrict__ Bt,
                                               const float* __restrict__ Res,
                                               float* __restrict__ C, int M, int N, int K) {
  __shared__ bf16 As[128 * 64];
  __shared__ bf16 Bs[128 * 64];
  const int t = threadIdx.x;
  const int lane = t & 63;
  const int w = t >> 6;
  const int wm = w >> 1, wn = w & 1;
  const int row0 = blockIdx.y * 128, col0 = blockIdx.x * 128;
  const int rm = lane & 15, qd = lane >> 4;
  f32x4 acc[4][4] = {};
  for (int k0 = 0; k0 < K; k0 += 64) {
#pragma unroll
    for (int i = 0; i < 4; ++i) {
      int c = i * 256 + t;                       // chunk id, 16B chunks; wave-uniform base
      int r = c >> 3, j = (c & 7) ^ (r & 7);     // XOR swizzle: phys chunk holds logical j
      gload_lds16(A + (size_t)(row0 + r) * K + (k0 + j * 8), &As[c * 8]);
      gload_lds16(Bt + (size_t)(col0 + r) * K + (k0 + j * 8), &Bs[c * 8]);
    }
    __syncthreads();
#pragma unroll
    for (int kb = 0; kb < 2; ++kb) {
      bf16x8 af[4], bfr[4];
#pragma unroll
      for (int mt = 0; mt < 4; ++mt) {
        int r = wm * 64 + mt * 16 + rm;
        af[mt] = *(const bf16x8*)&As[r * 64 + (((kb * 4 + qd) ^ (r & 7)) * 8)];
      }
#pragma unroll
      for (int nt = 0; nt < 4; ++nt) {
        int r = wn * 64 + nt * 16 + rm;
        bfr[nt] = *(const bf16x8*)&Bs[r * 64 + (((kb * 4 + qd) ^ (r & 7)) * 8)];
      }
#pragma unroll
      for (int mt = 0; mt < 4; ++mt)
#pragma unroll
        for (int nt = 0; nt < 4; ++nt)
          acc[mt][nt] = MFMA16(af[mt], bfr[nt], acc[mt][nt]);
    }
    __syncthreads();
  }
#pragma unroll
  for (int mt = 0; mt < 4; ++mt)
#pragma unroll
    for (int nt = 0; nt < 4; ++nt) {
      const int gc = col0 + wn * 64 + nt * 16 + rm;
#pragma unroll
      for (int r = 0; r < 4; ++r) {
        const int gr = row0 + wm * 64 + mt * 16 + qd * 4 + r;
        float v = acc[mt][nt][r];
        const size_t idx = (size_t)gr * N + gc;
        if (RES) v += Res[idx];
        C[idx] = v;
      }
    }
}

// ---------------------------------------------------------------------------
// RoPE + split qkv f32 [8192][2304] into head-major bf16 buffers
// Qb/Kb/Vb layout: [(b*12+h)*2048 + s][64]
// ---------------------------------------------------------------------------
__global__ __launch_bounds__(256) void rope_kernel(const float* __restrict__ qkv,
                                                   bf16* __restrict__ Qb, bf16* __restrict__ Kb,
                                                   bf16* __restrict__ Vb) {
  const int row = blockIdx.x;  // b*2048 + s
  const int s = row & 2047, b = row >> 11;
  const float* qr = qkv + (size_t)row * 2304;
  const int t = threadIdx.x;
#pragma unroll
  for (int i = 0; i < 3; ++i) {
    int idx = t + i * 256;     // 0..767 : 384 q-pairs then 384 k-pairs
    int which = idx >= 384;
    int pp = idx - which * 384;
    int h = pp >> 5, d = pp & 31;
    float invf = exp2f((float)d * -0.41524101186092029f);  // log2(10000)/32
    float ang = (float)s * invf;
    float cs, sn;
    sincosf(ang, &cs, &sn);
    float x1 = qr[which * 768 + h * 64 + d];
    float x2 = qr[which * 768 + h * 64 + d + 32];
    bf16* dst = (which ? Kb : Qb) + ((size_t)(b * 12 + h) * 2048 + s) * 64;
    dst[d] = (bf16)(x1 * cs - x2 * sn);
    dst[d + 32] = (bf16)(x2 * cs + x1 * sn);
  }
#pragma unroll
  for (int i = 0; i < 3; ++i) {
    int idx = t + i * 256;
    int h = idx >> 6, d = idx & 63;
    Vb[((size_t)(b * 12 + h) * 2048 + s) * 64 + d] = (bf16)qr[1536 + idx];
  }
}

// ---------------------------------------------------------------------------
// Sliding-window attention. Block = (b,h, 64-query tile). 256 threads / 4 waves.
// Wave w owns queries [w*16, w*16+16) over 192 staged keys (s0-64 .. s0+127).
// ctx out: [b*2048+s][h*64+d] bf16
// ---------------------------------------------------------------------------
__global__ __launch_bounds__(256) void attn_kernel(const bf16* __restrict__ Qb,
                                                   const bf16* __restrict__ Kb,
                                                   const bf16* __restrict__ Vb,
                                                   const float* __restrict__ am,
                                                   bf16* __restrict__ ctx) {
  __shared__ bf16 QKP[64 * 64 + 192 * 64];  // Qs | Ks; later aliased by Ps[64][208]
  __shared__ bf16 Vs[192 * 64];
  bf16* Qs = QKP;
  bf16* Ks = QKP + 64 * 64;
  bf16* Ps = QKP;

  const int t = threadIdx.x;
  const int lane = t & 63, w = t >> 6;
  const int rm = lane & 15, qd = lane >> 4;
  const int qt = blockIdx.x, bh = blockIdx.y;
  const int b = bh / 12, h = bh - b * 12;
  const int s0 = qt * 64;
  const size_t baseQ = (size_t)bh * 2048;

  // ---- stage Q (64 rows, swizzled), K (192 rows, swizzled), V (192 rows, plain)
#pragma unroll
  for (int i = 0; i < 2; ++i) {
    int c = i * 256 + t;
    int r = c >> 3, j = (c & 7) ^ (r & 7);
    gload_lds16(Qb + (baseQ + s0 + r) * 64 + j * 8, &Qs[c * 8]);
  }
#pragma unroll
  for (int i = 0; i < 6; ++i) {
    int c = i * 256 + t;
    int r = c >> 3;
    int key = s0 - 64 + r;
    key = min(max(key, 0), 2047);  // clamped rows are masked later
    int j = (c & 7) ^ (r & 7);
    gload_lds16(Kb + (baseQ + key) * 64 + j * 8, &Ks[c * 8]);
    gload_lds16(Vb + (baseQ + key) * 64 + (c & 7) * 8, &Vs[c * 8]);
  }
  __syncthreads();

  // ---- S = Q K^T (per wave: 1 m-tile x 12 n-tiles, K=64)
  bf16x8 aq[2];
#pragma unroll
  for (int kb = 0; kb < 2; ++kb) {
    int r = w * 16 + rm;
    aq[kb] = *(const bf16x8*)&Qs[r * 64 + (((kb * 4 + qd) ^ (r & 7)) * 8)];
  }
  f32x4 sc[12];
#pragma unroll
  for (int nt = 0; nt < 12; ++nt) {
    f32x4 a = {0.f, 0.f, 0.f, 0.f};
#pragma unroll
    for (int kb = 0; kb < 2; ++kb) {
      int r = nt * 16 + rm;
      bf16x8 bk = *(const bf16x8*)&Ks[r * 64 + (((kb * 4 + qd) ^ (r & 7)) * 8)];
      a = MFMA16(aq[kb], bk, a);
    }
    sc[nt] = a;
  }
  __syncthreads();  // all waves done with Qs/Ks; Ps may overwrite

  // ---- masked softmax in registers (C-frag: col=key=rm, row=query=qd*4+r)
  float mx[4] = {-1e38f, -1e38f, -1e38f, -1e38f};
#pragma unroll
  for (int nt = 0; nt < 12; ++nt) {
    int key = s0 - 64 + nt * 16 + rm;
#pragma unroll
    for (int r = 0; r < 4; ++r) {
      int qpos = s0 + w * 16 + qd * 4 + r;
      bool valid = (key >= 0) && (key < 2048) && (key - qpos <= 64) && (qpos - key <= 64);
      float v;
      if (valid)
        v = sc[nt][r] * 0.125f + am[((size_t)b * 2048 + qpos) * 2048 + key];
      else
        v = -1e38f;
      sc[nt][r] = v;
      mx[r] = fmaxf(mx[r], v);
    }
  }
#pragma unroll
  for (int r = 0; r < 4; ++r)
#pragma unroll
    for (int m = 1; m <= 8; m <<= 1) mx[r] = fmaxf(mx[r], __shfl_xor(mx[r], m, 64));
  float sum[4] = {0.f, 0.f, 0.f, 0.f};
#pragma unroll
  for (int nt = 0; nt < 12; ++nt)
#pragma unroll
    for (int r = 0; r < 4; ++r) {
      float p = (sc[nt][r] > -1e37f) ? __expf(sc[nt][r] - mx[r]) : 0.f;
      sc[nt][r] = p;
      sum[r] += p;
    }
#pragma unroll
  for (int r = 0; r < 4; ++r)
#pragma unroll
    for (int m = 1; m <= 8; m <<= 1) sum[r] += __shfl_xor(sum[r], m, 64);
  float inv[4];
#pragma unroll
  for (int r = 0; r < 4; ++r) inv[r] = 1.f / sum[r];
#pragma unroll
  for (int nt = 0; nt < 12; ++nt)
#pragma unroll
    for (int r = 0; r < 4; ++r)
      Ps[(w * 16 + qd * 4 + r) * 208 + nt * 16 + rm] = (bf16)(sc[nt][r] * inv[r]);
  __syncthreads();

  // ---- O = P V  (A from Ps rows [w*16, +16); B gathered from Vs[key][d])
  f32x4 o[4] = {};
#pragma unroll
  for (int ks = 0; ks < 6; ++ks) {
    bf16x8 ap = *(const bf16x8*)&Ps[(w * 16 + rm) * 208 + ks * 32 + qd * 8];
#pragma unroll
    for (int nt = 0; nt < 4; ++nt) {
      bf16x8 bv;
#pragma unroll
      for (int j = 0; j < 8; ++j) bv[j] = Vs[(ks * 32 + qd * 8 + j) * 64 + nt * 16 + rm];
      o[nt] = MFMA16(ap, bv, o[nt]);
    }
  }
#pragma unroll
  for (int nt = 0; nt < 4; ++nt)
#pragma unroll
    for (int r = 0; r < 4; ++r) {
      int q_ = s0 + w * 16 + qd * 4 + r;
      ctx[((size_t)(b * 2048 + q_)) * 768 + h * 64 + nt * 16 + rm] = (bf16)o[nt][r];
    }
}

// ---------------------------------------------------------------------------
// GeGLU: out = gelu(X[:, :1152]) * X[:, 1152:]  -> bf16
// ---------------------------------------------------------------------------
__global__ __launch_bounds__(128) void geglu_kernel(const float* __restrict__ X,
                                                    bf16* __restrict__ out) {
  const int row = blockIdx.y;
  const int c = blockIdx.x * 128 + threadIdx.x;
  const float* xr = X + (size_t)row * 2304;
  float x = xr[c], g = xr[1152 + c];
  float ge = 0.5f * x * (1.0f + erff(x * 0.70710678118654752f));
  out[(size_t)row * 1152 + c] = (bf16)(ge * g);
}

// ---------------------------------------------------------------------------
extern "C" void kernel_launch(void* const* d_in, const int* in_sizes, int n_in,
                              void* d_out, int out_size, void* d_ws, size_t ws_size,
                              hipStream_t stream) {
  (void)in_sizes; (void)n_in; (void)out_size; (void)ws_size;
  const float* hidden = (const float*)d_in[0];
  const float* amask = (const float*)d_in[1];
  const float* g1 = (const float*)d_in[2];
  const float* wqkv = (const float*)d_in[3];
  const float* woa = (const float*)d_in[4];
  const float* g2 = (const float*)d_in[5];
  const float* wi = (const float*)d_in[6];
  const float* wom = (const float*)d_in[7];
  float* out = (float*)d_out;

  char* p = (char*)d_ws;
  size_t o = 0;
  auto take = [&](size_t bytes) {
    char* r = p + o;
    o = (o + bytes + 255) & ~(size_t)255;
    return r;
  };
  bf16* wqkvT = (bf16*)take((size_t)2304 * 768 * 2);
  bf16* woaT = (bf16*)take((size_t)768 * 768 * 2);
  bf16* wiT = (bf16*)take((size_t)2304 * 768 * 2);
  bf16* womT = (bf16*)take((size_t)768 * 1152 * 2);
  bf16* xn = (bf16*)take((size_t)8192 * 768 * 2);        // LN out; reused for LN2 out
  float* qkv = (float*)take((size_t)8192 * 2304 * 4);    // qkv f32; reused for Wi out
  bf16* Qb = (bf16*)take((size_t)98304 * 64 * 2);
  bf16* Kb = (bf16*)take((size_t)98304 * 64 * 2);
  bf16* Vb = (bf16*)take((size_t)98304 * 64 * 2);
  bf16* ctxb = (bf16*)take((size_t)8192 * 768 * 2);
  float* hbuf = (float*)take((size_t)8192 * 768 * 4);
  bf16* mlp = (bf16*)take((size_t)8192 * 1152 * 2);

  // weights -> bf16 transposed [N][K]
  wconv_kernel<<<dim3(72, 24), 256, 0, stream>>>(wqkv, wqkvT, 768, 2304);
  wconv_kernel<<<dim3(24, 24), 256, 0, stream>>>(woa, woaT, 768, 768);
  wconv_kernel<<<dim3(72, 24), 256, 0, stream>>>(wi, wiT, 768, 2304);
  wconv_kernel<<<dim3(24, 36), 256, 0, stream>>>(wom, womT, 1152, 768);

  // attention half
  ln_kernel<<<8192, 256, 0, stream>>>(hidden, g1, xn);
  gemm_bt<false><<<dim3(18, 64), 256, 0, stream>>>(xn, wqkvT, nullptr, qkv, 8192, 2304, 768);
  rope_kernel<<<8192, 256, 0, stream>>>(qkv, Qb, Kb, Vb);
  attn_kernel<<<dim3(32, 48), 256, 0, stream>>>(Qb, Kb, Vb, amask, ctxb);
  gemm_bt<true><<<dim3(6, 64), 256, 0, stream>>>(ctxb, woaT, hidden, hbuf, 8192, 768, 768);

  // MLP half
  ln_kernel<<<8192, 256, 0, stream>>>(hbuf, g2, xn);
  gemm_bt<false><<<dim3(18, 64), 256, 0, stream>>>(xn, wiT, nullptr, qkv, 8192, 2304, 768);
  geglu_kernel<<<dim3(9, 8192), 128, 0, stream>>>(qkv, mlp);
  gemm_bt<true><<<dim3(6, 64), 256, 0, stream>>>(mlp, womT, hbuf, out, 8192, 768, 1152);
}

// Round 2
// 357.130 us; speedup vs baseline: 1.1713x; 1.1713x over previous
//
#include <hip/hip_runtime.h>
#include <cstdint>
#include <cstddef>

typedef __bf16 bf16;
typedef float f32x4 __attribute__((ext_vector_type(4)));
typedef __bf16 bf16x8 __attribute__((ext_vector_type(8)));

#define MFMA16(a, b, c) __builtin_amdgcn_mfma_f32_16x16x32_bf16((a), (b), (c), 0, 0, 0)

__device__ __forceinline__ void gload_lds16(const void* g, void* l) {
  __builtin_amdgcn_global_load_lds((__attribute__((address_space(1))) void*)g,
                                   (__attribute__((address_space(3))) void*)l,
                                   16, 0, 0);
}

// ---------------------------------------------------------------------------
// Weight transpose + f32->bf16 convert: W[K][N] -> Wt[N][K]
// ---------------------------------------------------------------------------
__global__ __launch_bounds__(256) void wconv_kernel(const float* __restrict__ W,
                                                    bf16* __restrict__ Wt, int K, int N) {
  __shared__ float tile[32][33];
  const int n0 = blockIdx.x * 32, k0 = blockIdx.y * 32;
  const int t = threadIdx.x;
  const int c = t & 31, r = t >> 5;
#pragma unroll
  for (int i = 0; i < 4; ++i)
    tile[r + i * 8][c] = W[(size_t)(k0 + r + i * 8) * N + n0 + c];
  __syncthreads();
#pragma unroll
  for (int i = 0; i < 4; ++i)
    Wt[(size_t)(n0 + r + i * 8) * K + k0 + c] = (bf16)tile[c][r + i * 8];
}

// ---------------------------------------------------------------------------
// LayerNorm (center=False): subtract mean, no beta -> bf16
// ---------------------------------------------------------------------------
__global__ __launch_bounds__(256) void ln_kernel(const float* __restrict__ X,
                                                 const float* __restrict__ gamma,
                                                 bf16* __restrict__ out) {
  const int row = blockIdx.x, t = threadIdx.x;
  const float* xr = X + (size_t)row * 768;
  float v0 = xr[t], v1 = xr[t + 256], v2 = xr[t + 512];
  float s = v0 + v1 + v2;
  float s2 = v0 * v0 + v1 * v1 + v2 * v2;
#pragma unroll
  for (int m = 1; m <= 32; m <<= 1) {
    s += __shfl_xor(s, m, 64);
    s2 += __shfl_xor(s2, m, 64);
  }
  __shared__ float red[8];
  const int w = t >> 6, lane = t & 63;
  if (lane == 0) { red[w] = s; red[4 + w] = s2; }
  __syncthreads();
  s = red[0] + red[1] + red[2] + red[3];
  s2 = red[4] + red[5] + red[6] + red[7];
  const float mu = s * (1.f / 768.f);
  const float var = s2 * (1.f / 768.f) - mu * mu;
  const float rs = rsqrtf(var + 1e-5f);
  out[(size_t)row * 768 + t] = (bf16)((v0 - mu) * rs * gamma[t]);
  out[(size_t)row * 768 + t + 256] = (bf16)((v1 - mu) * rs * gamma[t + 256]);
  out[(size_t)row * 768 + t + 512] = (bf16)((v2 - mu) * rs * gamma[t + 512]);
}

// ---------------------------------------------------------------------------
// NT GEMM: C[M][N] = A[M][K] * Bt[N][K]^T (+ optional f32 residual), TOUT out.
// Tile BM x 128, BK=64, 4 waves. BM=128: 2x2 waves of 64x64. BM=64: waves 32x64.
// ---------------------------------------------------------------------------
template <int BM, bool RES, typename TOUT>
__global__ __launch_bounds__(256) void gemm_bt(const bf16* __restrict__ A,
                                               const bf16* __restrict__ Bt,
                                               const float* __restrict__ Res,
                                               TOUT* __restrict__ C, int M, int N, int K) {
  constexpr int MT = BM / 32;  // m-frags per wave
  __shared__ __align__(16) bf16 As[BM * 64];
  __shared__ __align__(16) bf16 Bs[128 * 64];
  const int t = threadIdx.x;
  const int lane = t & 63;
  const int w = t >> 6;
  const int wm = w >> 1, wn = w & 1;
  const int row0 = blockIdx.y * BM, col0 = blockIdx.x * 128;
  const int rm = lane & 15, qd = lane >> 4;
  f32x4 acc[MT][4] = {};
  for (int k0 = 0; k0 < K; k0 += 64) {
#pragma unroll
    for (int i = 0; i < BM / 32; ++i) {
      int c = i * 256 + t;
      int r = c >> 3, j = (c & 7) ^ (r & 7);
      gload_lds16(A + (size_t)(row0 + r) * K + (k0 + j * 8), &As[c * 8]);
    }
#pragma unroll
    for (int i = 0; i < 4; ++i) {
      int c = i * 256 + t;
      int r = c >> 3, j = (c & 7) ^ (r & 7);
      gload_lds16(Bt + (size_t)(col0 + r) * K + (k0 + j * 8), &Bs[c * 8]);
    }
    __syncthreads();
#pragma unroll
    for (int kb = 0; kb < 2; ++kb) {
      bf16x8 af[MT], bfr[4];
#pragma unroll
      for (int mt = 0; mt < MT; ++mt) {
        int r = wm * (MT * 16) + mt * 16 + rm;
        af[mt] = *(const bf16x8*)&As[r * 64 + (((kb * 4 + qd) ^ (r & 7)) * 8)];
      }
#pragma unroll
      for (int nt = 0; nt < 4; ++nt) {
        int r = wn * 64 + nt * 16 + rm;
        bfr[nt] = *(const bf16x8*)&Bs[r * 64 + (((kb * 4 + qd) ^ (r & 7)) * 8)];
      }
#pragma unroll
      for (int mt = 0; mt < MT; ++mt)
#pragma unroll
        for (int nt = 0; nt < 4; ++nt)
          acc[mt][nt] = MFMA16(af[mt], bfr[nt], acc[mt][nt]);
    }
    __syncthreads();
  }
#pragma unroll
  for (int mt = 0; mt < MT; ++mt)
#pragma unroll
    for (int nt = 0; nt < 4; ++nt) {
      const int gc = col0 + wn * 64 + nt * 16 + rm;
#pragma unroll
      for (int r = 0; r < 4; ++r) {
        const int gr = row0 + wm * (MT * 16) + mt * 16 + qd * 4 + r;
        float v = acc[mt][nt][r];
        const size_t idx = (size_t)gr * N + gc;
        if (RES) v += Res[idx];
        C[idx] = (TOUT)v;
      }
    }
}

// ---------------------------------------------------------------------------
// RoPE on q,k from bf16 qkv [8192][2304]; out Qb/Kb [bh][s][64] bf16
// ---------------------------------------------------------------------------
__global__ __launch_bounds__(256) void rope_kernel(const bf16* __restrict__ qkv,
                                                   bf16* __restrict__ Qb,
                                                   bf16* __restrict__ Kb) {
  const int row = blockIdx.x;  // b*2048 + s
  const int s = row & 2047, b = row >> 11;
  const bf16* qr = qkv + (size_t)row * 2304;
  const int t = threadIdx.x;
#pragma unroll
  for (int i = 0; i < 3; ++i) {
    int idx = t + i * 256;     // 0..767 : 384 q-pairs then 384 k-pairs
    int which = idx >= 384;
    int pp = idx - which * 384;
    int h = pp >> 5, d = pp & 31;
    float invf = exp2f((float)d * -0.41524101186092029f);  // log2(10000)/32
    float ang = (float)s * invf;
    float cs, sn;
    sincosf(ang, &cs, &sn);
    float x1 = (float)qr[which * 768 + h * 64 + d];
    float x2 = (float)qr[which * 768 + h * 64 + d + 32];
    bf16* dst = (which ? Kb : Qb) + ((size_t)(b * 12 + h) * 2048 + s) * 64;
    dst[d] = (bf16)(x1 * cs - x2 * sn);
    dst[d + 32] = (bf16)(x2 * cs + x1 * sn);
  }
}

// ---------------------------------------------------------------------------
// V transpose: qkv bf16 v-part -> Vt[bh][d][s] bf16
// ---------------------------------------------------------------------------
__global__ __launch_bounds__(256) void vt_kernel(const bf16* __restrict__ qkv,
                                                 bf16* __restrict__ Vt) {
  const int bh = blockIdx.y, st = blockIdx.x;
  const int b = bh / 12, h = bh - b * 12;
  const int t = threadIdx.x, d = t & 63, sg = t >> 6;
  const int s0 = st * 64 + sg * 16;
  __align__(16) bf16 vals[16];
#pragma unroll
  for (int j = 0; j < 16; ++j)
    vals[j] = qkv[((size_t)(b * 2048 + s0 + j)) * 2304 + 1536 + h * 64 + d];
  bf16* dst = Vt + ((size_t)bh * 64 + d) * 2048 + s0;
  *(bf16x8*)&dst[0] = *(const bf16x8*)&vals[0];
  *(bf16x8*)&dst[8] = *(const bf16x8*)&vals[8];
}

// ---------------------------------------------------------------------------
// Sliding-window attention. Block = (64-query tile, bh). 256 thr / 4 waves.
// Wave w owns queries [s0+w*16, +16). Keys staged: [s0-64, s0+128).
// LDS: Ks [192key][64d] swizzled (24KB) -- aliased later by Ps[64][200] (25.6KB);
//      Vts [64d][192key] swizzled (24KB). Total 49KB -> 3 blocks/CU.
// ---------------------------------------------------------------------------
__global__ __launch_bounds__(256) void attn_kernel(const bf16* __restrict__ Qb,
                                                   const bf16* __restrict__ Kb,
                                                   const bf16* __restrict__ Vt,
                                                   const float* __restrict__ am,
                                                   bf16* __restrict__ ctx) {
  __shared__ __align__(16) bf16 KP[64 * 200];   // Ks (12288 el) then Ps (12800 el)
  __shared__ __align__(16) bf16 Vts[64 * 192];
  bf16* Ks = KP;
  bf16* Ps = KP;

  const int t = threadIdx.x;
  const int lane = t & 63, w = t >> 6;
  const int rm = lane & 15, qd = lane >> 4;
  const int s0 = blockIdx.x * 64;
  const int bh = blockIdx.y;
  const int b = bh / 12, h = bh - b * 12;
  const size_t baseQ = (size_t)bh * 2048;

  // ---- stage K rows [s0-64, s0+128) (row-clamped; clamped rows masked later)
#pragma unroll
  for (int i = 0; i < 6; ++i) {
    int c = i * 256 + t;
    int r = c >> 3, j = (c & 7) ^ (r & 7);
    int key = min(max(s0 - 64 + r, 0), 2047);
    gload_lds16(Kb + (baseQ + key) * 64 + j * 8, &Ks[c * 8]);
  }
  // ---- stage Vt tile: phys chunk c -> row r=c/24, logical col chunk XOR-swizzled
#pragma unroll
  for (int i = 0; i < 6; ++i) {
    int c = i * 256 + t;
    int r = c / 24, jl = c - r * 24;
    int j = (jl & 24) | ((jl & 7) ^ (r & 7));
    int k0 = min(max(s0 - 64 + j * 8, 0), 2040);  // whole-chunk clamp (8-aligned window)
    gload_lds16(Vt + ((size_t)bh * 64 + r) * 2048 + k0, &Vts[c * 8]);
  }

  // ---- Q fragments direct from global (16 queries per wave)
  bf16x8 aq[2];
#pragma unroll
  for (int kb = 0; kb < 2; ++kb)
    aq[kb] = *(const bf16x8*)&Qb[(baseQ + s0 + w * 16 + rm) * 64 + kb * 32 + qd * 8];

  // ---- prefetch attention-mask values (register-resident)
  float msk[12][4];
#pragma unroll
  for (int nt = 0; nt < 12; ++nt) {
    int key = s0 - 64 + nt * 16 + rm;
#pragma unroll
    for (int r = 0; r < 4; ++r) {
      int qpos = s0 + w * 16 + qd * 4 + r;
      bool valid = (key >= 0) && (key < 2048) && (key - qpos <= 64) && (qpos - key <= 64);
      msk[nt][r] = valid ? am[((size_t)b * 2048 + qpos) * 2048 + key] : -3e38f;
    }
  }
  __syncthreads();

  // ---- S = Q K^T
  f32x4 sc[12];
#pragma unroll
  for (int nt = 0; nt < 12; ++nt) {
    f32x4 a = {0.f, 0.f, 0.f, 0.f};
#pragma unroll
    for (int kb = 0; kb < 2; ++kb) {
      int r = nt * 16 + rm;
      bf16x8 bk = *(const bf16x8*)&Ks[r * 64 + (((kb * 4 + qd) ^ (rm & 7)) * 8)];
      a = MFMA16(aq[kb], bk, a);
    }
    sc[nt] = a;
  }

  // ---- masked softmax (C-frag: col=key=rm-tile, row=query=qd*4+r)
  float mx[4] = {-3e38f, -3e38f, -3e38f, -3e38f};
#pragma unroll
  for (int nt = 0; nt < 12; ++nt)
#pragma unroll
    for (int r = 0; r < 4; ++r) {
      float v = (msk[nt][r] <= -2.9e38f) ? -3e38f : sc[nt][r] * 0.125f + msk[nt][r];
      sc[nt][r] = v;
      mx[r] = fmaxf(mx[r], v);
    }
#pragma unroll
  for (int r = 0; r < 4; ++r)
#pragma unroll
    for (int m = 1; m <= 8; m <<= 1) mx[r] = fmaxf(mx[r], __shfl_xor(mx[r], m, 64));
  float sum[4] = {0.f, 0.f, 0.f, 0.f};
#pragma unroll
  for (int nt = 0; nt < 12; ++nt)
#pragma unroll
    for (int r = 0; r < 4; ++r) {
      float p = (sc[nt][r] > -1e37f) ? __expf(sc[nt][r] - mx[r]) : 0.f;
      sc[nt][r] = p;
      sum[r] += p;
    }
#pragma unroll
  for (int r = 0; r < 4; ++r)
#pragma unroll
    for (int m = 1; m <= 8; m <<= 1) sum[r] += __shfl_xor(sum[r], m, 64);
  float inv[4];
#pragma unroll
  for (int r = 0; r < 4; ++r) inv[r] = 1.f / sum[r];

  __syncthreads();  // all waves done reading Ks; Ps overwrites

  // ---- P -> LDS (own-wave rows only; no barrier needed before PV)
#pragma unroll
  for (int nt = 0; nt < 12; ++nt)
#pragma unroll
    for (int r = 0; r < 4; ++r)
      Ps[(w * 16 + qd * 4 + r) * 200 + nt * 16 + rm] = (bf16)(sc[nt][r] * inv[r]);

  // ---- O = P V  (A: Ps rows of own wave; B: Vts rows, swizzled vector reads)
  f32x4 o[4] = {};
#pragma unroll
  for (int ks = 0; ks < 6; ++ks) {
    bf16x8 ap = *(const bf16x8*)&Ps[(w * 16 + rm) * 200 + ks * 32 + qd * 8];
#pragma unroll
    for (int nt = 0; nt < 4; ++nt) {
      int kc = ks * 4 + qd;
      bf16x8 bv = *(const bf16x8*)&Vts[(nt * 16 + rm) * 192 +
                                       (((kc & 24) | ((kc & 7) ^ (rm & 7))) * 8)];
      o[nt] = MFMA16(ap, bv, o[nt]);
    }
  }
#pragma unroll
  for (int nt = 0; nt < 4; ++nt)
#pragma unroll
    for (int r = 0; r < 4; ++r) {
      int q_ = s0 + w * 16 + qd * 4 + r;
      ctx[((size_t)(b * 2048 + q_)) * 768 + h * 64 + nt * 16 + rm] = (bf16)o[nt][r];
    }
}

// ---------------------------------------------------------------------------
// GeGLU: out = gelu(X[:, :1152]) * X[:, 1152:]  (bf16 in/out)
// ---------------------------------------------------------------------------
__global__ __launch_bounds__(128) void geglu_kernel(const bf16* __restrict__ X,
                                                    bf16* __restrict__ out) {
  const int row = blockIdx.y;
  const int c = blockIdx.x * 128 + threadIdx.x;
  const bf16* xr = X + (size_t)row * 2304;
  float x = (float)xr[c], g = (float)xr[1152 + c];
  float ge = 0.5f * x * (1.0f + erff(x * 0.70710678118654752f));
  out[(size_t)row * 1152 + c] = (bf16)(ge * g);
}

// ---------------------------------------------------------------------------
extern "C" void kernel_launch(void* const* d_in, const int* in_sizes, int n_in,
                              void* d_out, int out_size, void* d_ws, size_t ws_size,
                              hipStream_t stream) {
  (void)in_sizes; (void)n_in; (void)out_size; (void)ws_size;
  const float* hidden = (const float*)d_in[0];
  const float* amask = (const float*)d_in[1];
  const float* g1 = (const float*)d_in[2];
  const float* wqkv = (const float*)d_in[3];
  const float* woa = (const float*)d_in[4];
  const float* g2 = (const float*)d_in[5];
  const float* wi = (const float*)d_in[6];
  const float* wom = (const float*)d_in[7];
  float* out = (float*)d_out;

  char* p = (char*)d_ws;
  size_t o = 0;
  auto take = [&](size_t bytes) {
    char* r = p + o;
    o = (o + bytes + 255) & ~(size_t)255;
    return r;
  };
  bf16* wqkvT = (bf16*)take((size_t)2304 * 768 * 2);
  bf16* woaT = (bf16*)take((size_t)768 * 768 * 2);
  bf16* wiT = (bf16*)take((size_t)2304 * 768 * 2);
  bf16* womT = (bf16*)take((size_t)768 * 1152 * 2);
  bf16* xn = (bf16*)take((size_t)8192 * 768 * 2);      // LN out (reused for LN2)
  bf16* qkvb = (bf16*)take((size_t)8192 * 2304 * 2);   // qkv bf16; reused for Wi out
  bf16* Qb = (bf16*)take((size_t)98304 * 64 * 2);
  bf16* Kb = (bf16*)take((size_t)98304 * 64 * 2);
  bf16* Vt = (bf16*)take((size_t)98304 * 64 * 2);      // [bh][d][s]
  bf16* ctxb = (bf16*)take((size_t)8192 * 768 * 2);
  float* hbuf = (float*)take((size_t)8192 * 768 * 4);
  bf16* mlp = (bf16*)take((size_t)8192 * 1152 * 2);

  // weights -> bf16 transposed [N][K]
  wconv_kernel<<<dim3(72, 24), 256, 0, stream>>>(wqkv, wqkvT, 768, 2304);
  wconv_kernel<<<dim3(24, 24), 256, 0, stream>>>(woa, woaT, 768, 768);
  wconv_kernel<<<dim3(72, 24), 256, 0, stream>>>(wi, wiT, 768, 2304);
  wconv_kernel<<<dim3(24, 36), 256, 0, stream>>>(wom, womT, 1152, 768);

  // attention half
  ln_kernel<<<8192, 256, 0, stream>>>(hidden, g1, xn);
  gemm_bt<128, false, bf16><<<dim3(18, 64), 256, 0, stream>>>(xn, wqkvT, nullptr, qkvb,
                                                              8192, 2304, 768);
  rope_kernel<<<8192, 256, 0, stream>>>(qkvb, Qb, Kb);
  vt_kernel<<<dim3(32, 48), 256, 0, stream>>>(qkvb, Vt);
  attn_kernel<<<dim3(32, 48), 256, 0, stream>>>(Qb, Kb, Vt, amask, ctxb);
  gemm_bt<64, true, float><<<dim3(6, 128), 256, 0, stream>>>(ctxb, woaT, hidden, hbuf,
                                                             8192, 768, 768);

  // MLP half
  ln_kernel<<<8192, 256, 0, stream>>>(hbuf, g2, xn);
  gemm_bt<128, false, bf16><<<dim3(18, 64), 256, 0, stream>>>(xn, wiT, nullptr, qkvb,
                                                              8192, 2304, 768);
  geglu_kernel<<<dim3(9, 8192), 128, 0, stream>>>(qkvb, mlp);
  gemm_bt<64, true, float><<<dim3(6, 128), 256, 0, stream>>>(mlp, womT, hbuf, out,
                                                             8192, 768, 1152);
}

// Round 3
// 329.510 us; speedup vs baseline: 1.2695x; 1.0838x over previous
//
#include <hip/hip_runtime.h>
#include <cstdint>
#include <cstddef>

typedef __bf16 bf16;
typedef float f32x4 __attribute__((ext_vector_type(4)));
typedef __bf16 bf16x8 __attribute__((ext_vector_type(8)));
typedef __bf16 bf16x4 __attribute__((ext_vector_type(4)));

#define MFMA16(a, b, c) __builtin_amdgcn_mfma_f32_16x16x32_bf16((a), (b), (c), 0, 0, 0)

__device__ __forceinline__ void gload_lds16(const void* g, void* l) {
  __builtin_amdgcn_global_load_lds((__attribute__((address_space(1))) void*)g,
                                   (__attribute__((address_space(3))) void*)l,
                                   16, 0, 0);
}

// ---------------------------------------------------------------------------
// Weight transpose + f32->bf16 convert: W[K][N] -> Wt[N][K]
// ---------------------------------------------------------------------------
__global__ __launch_bounds__(256) void wconv_kernel(const float* __restrict__ W,
                                                    bf16* __restrict__ Wt, int K, int N) {
  __shared__ float tile[32][33];
  const int n0 = blockIdx.x * 32, k0 = blockIdx.y * 32;
  const int t = threadIdx.x;
  const int c = t & 31, r = t >> 5;
#pragma unroll
  for (int i = 0; i < 4; ++i)
    tile[r + i * 8][c] = W[(size_t)(k0 + r + i * 8) * N + n0 + c];
  __syncthreads();
#pragma unroll
  for (int i = 0; i < 4; ++i)
    Wt[(size_t)(n0 + r + i * 8) * K + k0 + c] = (bf16)tile[c][r + i * 8];
}

// ---------------------------------------------------------------------------
// LayerNorm (center=False): subtract mean, no beta -> bf16
// ---------------------------------------------------------------------------
__global__ __launch_bounds__(256) void ln_kernel(const float* __restrict__ X,
                                                 const float* __restrict__ gamma,
                                                 bf16* __restrict__ out) {
  const int row = blockIdx.x, t = threadIdx.x;
  const float* xr = X + (size_t)row * 768;
  float v0 = xr[t], v1 = xr[t + 256], v2 = xr[t + 512];
  float s = v0 + v1 + v2;
  float s2 = v0 * v0 + v1 * v1 + v2 * v2;
#pragma unroll
  for (int m = 1; m <= 32; m <<= 1) {
    s += __shfl_xor(s, m, 64);
    s2 += __shfl_xor(s2, m, 64);
  }
  __shared__ float red[8];
  const int w = t >> 6, lane = t & 63;
  if (lane == 0) { red[w] = s; red[4 + w] = s2; }
  __syncthreads();
  s = red[0] + red[1] + red[2] + red[3];
  s2 = red[4] + red[5] + red[6] + red[7];
  const float mu = s * (1.f / 768.f);
  const float var = s2 * (1.f / 768.f) - mu * mu;
  const float rs = rsqrtf(var + 1e-5f);
  out[(size_t)row * 768 + t] = (bf16)((v0 - mu) * rs * gamma[t]);
  out[(size_t)row * 768 + t + 256] = (bf16)((v1 - mu) * rs * gamma[t + 256]);
  out[(size_t)row * 768 + t + 512] = (bf16)((v2 - mu) * rs * gamma[t + 512]);
}

// ---------------------------------------------------------------------------
// Generic NT GEMM: C[M][N] = A * Bt^T (+ f32 residual), TOUT out.
// ---------------------------------------------------------------------------
template <int BM, bool RES, typename TOUT>
__global__ __launch_bounds__(256) void gemm_bt(const bf16* __restrict__ A,
                                               const bf16* __restrict__ Bt,
                                               const float* __restrict__ Res,
                                               TOUT* __restrict__ C, int M, int N, int K) {
  constexpr int MT = BM / 32;
  __shared__ __align__(16) bf16 As[BM * 64];
  __shared__ __align__(16) bf16 Bs[128 * 64];
  const int t = threadIdx.x;
  const int lane = t & 63;
  const int w = t >> 6;
  const int wm = w >> 1, wn = w & 1;
  const int row0 = blockIdx.y * BM, col0 = blockIdx.x * 128;
  const int rm = lane & 15, qd = lane >> 4;
  f32x4 acc[MT][4] = {};
  for (int k0 = 0; k0 < K; k0 += 64) {
#pragma unroll
    for (int i = 0; i < BM / 32; ++i) {
      int c = i * 256 + t;
      int r = c >> 3, j = (c & 7) ^ (r & 7);
      gload_lds16(A + (size_t)(row0 + r) * K + (k0 + j * 8), &As[c * 8]);
    }
#pragma unroll
    for (int i = 0; i < 4; ++i) {
      int c = i * 256 + t;
      int r = c >> 3, j = (c & 7) ^ (r & 7);
      gload_lds16(Bt + (size_t)(col0 + r) * K + (k0 + j * 8), &Bs[c * 8]);
    }
    __syncthreads();
#pragma unroll
    for (int kb = 0; kb < 2; ++kb) {
      bf16x8 af[MT], bfr[4];
#pragma unroll
      for (int mt = 0; mt < MT; ++mt) {
        int r = wm * (MT * 16) + mt * 16 + rm;
        af[mt] = *(const bf16x8*)&As[r * 64 + (((kb * 4 + qd) ^ (r & 7)) * 8)];
      }
#pragma unroll
      for (int nt = 0; nt < 4; ++nt) {
        int r = wn * 64 + nt * 16 + rm;
        bfr[nt] = *(const bf16x8*)&Bs[r * 64 + (((kb * 4 + qd) ^ (r & 7)) * 8)];
      }
#pragma unroll
      for (int mt = 0; mt < MT; ++mt)
#pragma unroll
        for (int nt = 0; nt < 4; ++nt)
          acc[mt][nt] = MFMA16(af[mt], bfr[nt], acc[mt][nt]);
    }
    __syncthreads();
  }
#pragma unroll
  for (int mt = 0; mt < MT; ++mt)
#pragma unroll
    for (int nt = 0; nt < 4; ++nt) {
      const int gc = col0 + wn * 64 + nt * 16 + rm;
#pragma unroll
      for (int r = 0; r < 4; ++r) {
        const int gr = row0 + wm * (MT * 16) + mt * 16 + qd * 4 + r;
        float v = acc[mt][nt][r];
        const size_t idx = (size_t)gr * N + gc;
        if (RES) v += Res[idx];
        C[idx] = (TOUT)v;
      }
    }
}

// ---------------------------------------------------------------------------
// QKV GEMM with fused RoPE + head-split + V-transpose epilogue.
// A = xn [8192][768] bf16, Bt = wqkvT [2304][768] bf16.
// Each wave's 64-col span == exactly one head (col0=blockIdx.x*128, 2 heads/blk).
// Outputs: Qb/Kb [bh][s][64] (RoPE'd), Vt [bh][d][s].
// ---------------------------------------------------------------------------
__global__ __launch_bounds__(256) void gemm_qkv(const bf16* __restrict__ A,
                                                const bf16* __restrict__ Bt,
                                                bf16* __restrict__ Qb,
                                                bf16* __restrict__ Kb,
                                                bf16* __restrict__ Vt) {
  __shared__ __align__(16) bf16 As[128 * 64];
  __shared__ __align__(16) bf16 Bs[128 * 64];
  const int t = threadIdx.x;
  const int lane = t & 63;
  const int w = t >> 6;
  const int wm = w >> 1, wn = w & 1;
  const int row0 = blockIdx.y * 128, col0 = blockIdx.x * 128;
  const int rm = lane & 15, qd = lane >> 4;
  f32x4 acc[4][4] = {};
  for (int k0 = 0; k0 < 768; k0 += 64) {
#pragma unroll
    for (int i = 0; i < 4; ++i) {
      int c = i * 256 + t;
      int r = c >> 3, j = (c & 7) ^ (r & 7);
      gload_lds16(A + (size_t)(row0 + r) * 768 + (k0 + j * 8), &As[c * 8]);
      int c2 = i * 256 + t;
      gload_lds16(Bt + (size_t)(col0 + r) * 768 + (k0 + j * 8), &Bs[c2 * 8]);
    }
    __syncthreads();
#pragma unroll
    for (int kb = 0; kb < 2; ++kb) {
      bf16x8 af[4], bfr[4];
#pragma unroll
      for (int mt = 0; mt < 4; ++mt) {
        int r = wm * 64 + mt * 16 + rm;
        af[mt] = *(const bf16x8*)&As[r * 64 + (((kb * 4 + qd) ^ (r & 7)) * 8)];
      }
#pragma unroll
      for (int nt = 0; nt < 4; ++nt) {
        int r = wn * 64 + nt * 16 + rm;
        bfr[nt] = *(const bf16x8*)&Bs[r * 64 + (((kb * 4 + qd) ^ (r & 7)) * 8)];
      }
#pragma unroll
      for (int mt = 0; mt < 4; ++mt)
#pragma unroll
        for (int nt = 0; nt < 4; ++nt)
          acc[mt][nt] = MFMA16(af[mt], bfr[nt], acc[mt][nt]);
    }
    __syncthreads();
  }

  // ---- fused epilogue
  const int head_id = blockIdx.x * 2 + wn;  // 0..35
  const int typ = head_id / 12;             // 0=q 1=k 2=v
  const int h = head_id - typ * 12;
  const int b = row0 >> 11;
  const int sw = (row0 & 2047) + wm * 64;   // wave s-base
  const size_t bhbase = (size_t)(b * 12 + h) * 2048;

  if (typ < 2) {
    bf16* dst = typ ? Kb : Qb;
    float invf[2];
#pragma unroll
    for (int nt = 0; nt < 2; ++nt)
      invf[nt] = exp2f((float)(nt * 16 + rm) * -0.41524101186092029f);  // 10000^(-d/32)
#pragma unroll
    for (int mt = 0; mt < 4; ++mt)
#pragma unroll
      for (int r = 0; r < 4; ++r) {
        int s = sw + mt * 16 + qd * 4 + r;
#pragma unroll
        for (int nt = 0; nt < 2; ++nt) {
          float ang = (float)s * invf[nt];
          float rev = ang * 0.15915494309189535f;
          rev -= floorf(rev);  // reduce to [0,1) revolutions
          float sn = __builtin_amdgcn_sinf(rev);
          float cs = __builtin_amdgcn_cosf(rev);
          float x1 = acc[mt][nt][r], x2 = acc[mt][nt + 2][r];
          int d = nt * 16 + rm;
          dst[(bhbase + s) * 64 + d] = (bf16)(x1 * cs - x2 * sn);
          dst[(bhbase + s) * 64 + d + 32] = (bf16)(x2 * cs + x1 * sn);
        }
      }
  } else {
#pragma unroll
    for (int mt = 0; mt < 4; ++mt)
#pragma unroll
      for (int nt = 0; nt < 4; ++nt) {
        int d = nt * 16 + rm;
        int s4 = sw + mt * 16 + qd * 4;  // 4 consecutive s
        bf16x4 v4;
#pragma unroll
        for (int r = 0; r < 4; ++r) v4[r] = (bf16)acc[mt][nt][r];
        *(bf16x4*)&Vt[(bhbase * 64) + ((size_t)(h * 0) ) + ((size_t)( (b * 12 + h) * 64 + d)) * 2048 + s4 - bhbase * 64] = v4;
      }
  }
}

// ---------------------------------------------------------------------------
// Wi GEMM with fused GeGLU. A = xn2 [8192][768], Bt = wiT [2304][768].
// Block: 128 rows x (64 x-cols [c0..] + 64 gate-cols [1152+c0..]).
// out mlp [8192][1152] bf16 = gelu(x)*gate.
// ---------------------------------------------------------------------------
__global__ __launch_bounds__(256) void gemm_wi_geglu(const bf16* __restrict__ A,
                                                     const bf16* __restrict__ Bt,
                                                     bf16* __restrict__ outp) {
  __shared__ __align__(16) bf16 As[128 * 64];
  __shared__ __align__(16) bf16 Bxs[64 * 64];
  __shared__ __align__(16) bf16 Bgs[64 * 64];
  const int t = threadIdx.x;
  const int lane = t & 63;
  const int w = t >> 6;
  const int wm = w >> 1, wn = w & 1;
  const int row0 = blockIdx.y * 128, col0 = blockIdx.x * 64;  // 18 col-tiles of 64
  const int rm = lane & 15, qd = lane >> 4;
  f32x4 accx[4][2] = {}, accg[4][2] = {};
  for (int k0 = 0; k0 < 768; k0 += 64) {
#pragma unroll
    for (int i = 0; i < 4; ++i) {
      int c = i * 256 + t;
      int r = c >> 3, j = (c & 7) ^ (r & 7);
      gload_lds16(A + (size_t)(row0 + r) * 768 + (k0 + j * 8), &As[c * 8]);
    }
#pragma unroll
    for (int i = 0; i < 2; ++i) {
      int c = i * 256 + t;
      int r = c >> 3, j = (c & 7) ^ (r & 7);
      gload_lds16(Bt + (size_t)(col0 + r) * 768 + (k0 + j * 8), &Bxs[c * 8]);
      gload_lds16(Bt + (size_t)(1152 + col0 + r) * 768 + (k0 + j * 8), &Bgs[c * 8]);
    }
    __syncthreads();
#pragma unroll
    for (int kb = 0; kb < 2; ++kb) {
      bf16x8 af[4], bx[2], bg[2];
#pragma unroll
      for (int mt = 0; mt < 4; ++mt) {
        int r = wm * 64 + mt * 16 + rm;
        af[mt] = *(const bf16x8*)&As[r * 64 + (((kb * 4 + qd) ^ (r & 7)) * 8)];
      }
#pragma unroll
      for (int nt = 0; nt < 2; ++nt) {
        int r = wn * 32 + nt * 16 + rm;
        int off = r * 64 + (((kb * 4 + qd) ^ (r & 7)) * 8);
        bx[nt] = *(const bf16x8*)&Bxs[off];
        bg[nt] = *(const bf16x8*)&Bgs[off];
      }
#pragma unroll
      for (int mt = 0; mt < 4; ++mt)
#pragma unroll
        for (int nt = 0; nt < 2; ++nt) {
          accx[mt][nt] = MFMA16(af[mt], bx[nt], accx[mt][nt]);
          accg[mt][nt] = MFMA16(af[mt], bg[nt], accg[mt][nt]);
        }
    }
    __syncthreads();
  }
#pragma unroll
  for (int mt = 0; mt < 4; ++mt)
#pragma unroll
    for (int nt = 0; nt < 2; ++nt) {
      const int gc = col0 + wn * 32 + nt * 16 + rm;
#pragma unroll
      for (int r = 0; r < 4; ++r) {
        const int gr = row0 + wm * 64 + mt * 16 + qd * 4 + r;
        float x = accx[mt][nt][r], g = accg[mt][nt][r];
        float ge = 0.5f * x * (1.0f + erff(x * 0.70710678118654752f));
        outp[(size_t)gr * 1152 + gc] = (bf16)(ge * g);
      }
    }
}

// ---------------------------------------------------------------------------
// Sliding-window attention (unchanged from round 2 — passes, ~fast).
// ---------------------------------------------------------------------------
__global__ __launch_bounds__(256) void attn_kernel(const bf16* __restrict__ Qb,
                                                   const bf16* __restrict__ Kb,
                                                   const bf16* __restrict__ Vt,
                                                   const float* __restrict__ am,
                                                   bf16* __restrict__ ctx) {
  __shared__ __align__(16) bf16 KP[64 * 200];
  __shared__ __align__(16) bf16 Vts[64 * 192];
  bf16* Ks = KP;
  bf16* Ps = KP;

  const int t = threadIdx.x;
  const int lane = t & 63, w = t >> 6;
  const int rm = lane & 15, qd = lane >> 4;
  const int s0 = blockIdx.x * 64;
  const int bh = blockIdx.y;
  const int b = bh / 12, h = bh - b * 12;
  const size_t baseQ = (size_t)bh * 2048;

#pragma unroll
  for (int i = 0; i < 6; ++i) {
    int c = i * 256 + t;
    int r = c >> 3, j = (c & 7) ^ (r & 7);
    int key = min(max(s0 - 64 + r, 0), 2047);
    gload_lds16(Kb + (baseQ + key) * 64 + j * 8, &Ks[c * 8]);
  }
#pragma unroll
  for (int i = 0; i < 6; ++i) {
    int c = i * 256 + t;
    int r = c / 24, jl = c - r * 24;
    int j = (jl & 24) | ((jl & 7) ^ (r & 7));
    int k0 = min(max(s0 - 64 + j * 8, 0), 2040);
    gload_lds16(Vt + ((size_t)bh * 64 + r) * 2048 + k0, &Vts[c * 8]);
  }

  bf16x8 aq[2];
#pragma unroll
  for (int kb = 0; kb < 2; ++kb)
    aq[kb] = *(const bf16x8*)&Qb[(baseQ + s0 + w * 16 + rm) * 64 + kb * 32 + qd * 8];

  float msk[12][4];
#pragma unroll
  for (int nt = 0; nt < 12; ++nt) {
    int key = s0 - 64 + nt * 16 + rm;
#pragma unroll
    for (int r = 0; r < 4; ++r) {
      int qpos = s0 + w * 16 + qd * 4 + r;
      bool valid = (key >= 0) && (key < 2048) && (key - qpos <= 64) && (qpos - key <= 64);
      msk[nt][r] = valid ? am[((size_t)b * 2048 + qpos) * 2048 + key] : -3e38f;
    }
  }
  __syncthreads();

  f32x4 sc[12];
#pragma unroll
  for (int nt = 0; nt < 12; ++nt) {
    f32x4 a = {0.f, 0.f, 0.f, 0.f};
#pragma unroll
    for (int kb = 0; kb < 2; ++kb) {
      int r = nt * 16 + rm;
      bf16x8 bk = *(const bf16x8*)&Ks[r * 64 + (((kb * 4 + qd) ^ (rm & 7)) * 8)];
      a = MFMA16(aq[kb], bk, a);
    }
    sc[nt] = a;
  }

  float mx[4] = {-3e38f, -3e38f, -3e38f, -3e38f};
#pragma unroll
  for (int nt = 0; nt < 12; ++nt)
#pragma unroll
    for (int r = 0; r < 4; ++r) {
      float v = (msk[nt][r] <= -2.9e38f) ? -3e38f : sc[nt][r] * 0.125f + msk[nt][r];
      sc[nt][r] = v;
      mx[r] = fmaxf(mx[r], v);
    }
#pragma unroll
  for (int r = 0; r < 4; ++r)
#pragma unroll
    for (int m = 1; m <= 8; m <<= 1) mx[r] = fmaxf(mx[r], __shfl_xor(mx[r], m, 64));
  float sum[4] = {0.f, 0.f, 0.f, 0.f};
#pragma unroll
  for (int nt = 0; nt < 12; ++nt)
#pragma unroll
    for (int r = 0; r < 4; ++r) {
      float p = (sc[nt][r] > -1e37f) ? __expf(sc[nt][r] - mx[r]) : 0.f;
      sc[nt][r] = p;
      sum[r] += p;
    }
#pragma unroll
  for (int r = 0; r < 4; ++r)
#pragma unroll
    for (int m = 1; m <= 8; m <<= 1) sum[r] += __shfl_xor(sum[r], m, 64);
  float inv[4];
#pragma unroll
  for (int r = 0; r < 4; ++r) inv[r] = 1.f / sum[r];

  __syncthreads();

#pragma unroll
  for (int nt = 0; nt < 12; ++nt)
#pragma unroll
    for (int r = 0; r < 4; ++r)
      Ps[(w * 16 + qd * 4 + r) * 200 + nt * 16 + rm] = (bf16)(sc[nt][r] * inv[r]);

  f32x4 o[4] = {};
#pragma unroll
  for (int ks = 0; ks < 6; ++ks) {
    bf16x8 ap = *(const bf16x8*)&Ps[(w * 16 + rm) * 200 + ks * 32 + qd * 8];
#pragma unroll
    for (int nt = 0; nt < 4; ++nt) {
      int kc = ks * 4 + qd;
      bf16x8 bv = *(const bf16x8*)&Vts[(nt * 16 + rm) * 192 +
                                       (((kc & 24) | ((kc & 7) ^ (rm & 7))) * 8)];
      o[nt] = MFMA16(ap, bv, o[nt]);
    }
  }
#pragma unroll
  for (int nt = 0; nt < 4; ++nt)
#pragma unroll
    for (int r = 0; r < 4; ++r) {
      int q_ = s0 + w * 16 + qd * 4 + r;
      ctx[((size_t)(b * 2048 + q_)) * 768 + h * 64 + nt * 16 + rm] = (bf16)o[nt][r];
    }
}

// ---------------------------------------------------------------------------
extern "C" void kernel_launch(void* const* d_in, const int* in_sizes, int n_in,
                              void* d_out, int out_size, void* d_ws, size_t ws_size,
                              hipStream_t stream) {
  (void)in_sizes; (void)n_in; (void)out_size; (void)ws_size;
  const float* hidden = (const float*)d_in[0];
  const float* amask = (const float*)d_in[1];
  const float* g1 = (const float*)d_in[2];
  const float* wqkv = (const float*)d_in[3];
  const float* woa = (const float*)d_in[4];
  const float* g2 = (const float*)d_in[5];
  const float* wi = (const float*)d_in[6];
  const float* wom = (const float*)d_in[7];
  float* out = (float*)d_out;

  char* p = (char*)d_ws;
  size_t o = 0;
  auto take = [&](size_t bytes) {
    char* r = p + o;
    o = (o + bytes + 255) & ~(size_t)255;
    return r;
  };
  bf16* wqkvT = (bf16*)take((size_t)2304 * 768 * 2);
  bf16* woaT = (bf16*)take((size_t)768 * 768 * 2);
  bf16* wiT = (bf16*)take((size_t)2304 * 768 * 2);
  bf16* womT = (bf16*)take((size_t)768 * 1152 * 2);
  bf16* xn = (bf16*)take((size_t)8192 * 768 * 2);   // LN out (reused for LN2)
  bf16* Qb = (bf16*)take((size_t)98304 * 64 * 2);
  bf16* Kb = (bf16*)take((size_t)98304 * 64 * 2);
  bf16* Vt = (bf16*)take((size_t)98304 * 64 * 2);   // [bh][d][s]
  bf16* ctxb = (bf16*)take((size_t)8192 * 768 * 2);
  float* hbuf = (float*)take((size_t)8192 * 768 * 4);
  bf16* mlp = (bf16*)take((size_t)8192 * 1152 * 2);

  // weights -> bf16 transposed [N][K]
  wconv_kernel<<<dim3(72, 24), 256, 0, stream>>>(wqkv, wqkvT, 768, 2304);
  wconv_kernel<<<dim3(24, 24), 256, 0, stream>>>(woa, woaT, 768, 768);
  wconv_kernel<<<dim3(72, 24), 256, 0, stream>>>(wi, wiT, 768, 2304);
  wconv_kernel<<<dim3(24, 36), 256, 0, stream>>>(wom, womT, 1152, 768);

  // attention half
  ln_kernel<<<8192, 256, 0, stream>>>(hidden, g1, xn);
  gemm_qkv<<<dim3(18, 64), 256, 0, stream>>>(xn, wqkvT, Qb, Kb, Vt);
  attn_kernel<<<dim3(32, 48), 256, 0, stream>>>(Qb, Kb, Vt, amask, ctxb);
  gemm_bt<64, true, float><<<dim3(6, 128), 256, 0, stream>>>(ctxb, woaT, hidden, hbuf,
                                                             8192, 768, 768);

  // MLP half
  ln_kernel<<<8192, 256, 0, stream>>>(hbuf, g2, xn);
  gemm_wi_geglu<<<dim3(18, 64), 256, 0, stream>>>(xn, wiT, mlp);
  gemm_bt<64, true, float><<<dim3(6, 128), 256, 0, stream>>>(mlp, womT, hbuf, out,
                                                             8192, 768, 1152);
}